// Round 9
// baseline (4263.314 us; speedup 1.0000x reference)
//
#include <hip/hip_runtime.h>
#include <cmath>

#define S_LEN 32
#define E_DIM 128
#define H_DIM 256
#define V_DIM 512
#define NTILE 36            // BK=64: pass1 18 (a1 x w1w2w3), pass2 12, pass3 6
#define TILE_SHORTS 8192    // 16 frags x 64 lanes x 8 shorts = 16 KB
#define A_SHORTS 24576      // 12 ksub x 4 rowblk x 64 lanes x 8 = 48 KB

typedef __attribute__((ext_vector_type(8))) short bf16x8v;
typedef __attribute__((ext_vector_type(4))) float f32x4v;

__device__ __forceinline__ float sigf(float x) { return 1.0f / (1.0f + expf(-x)); }

__device__ __forceinline__ unsigned short f2bf(float x) {      // RNE
  unsigned int b = __float_as_uint(x);
  b += 0x7FFFu + ((b >> 16) & 1u);
  return (unsigned short)(b >> 16);
}
__device__ __forceinline__ float bf2f(unsigned short u) {
  return __uint_as_float(((unsigned int)u) << 16);
}

template<int L>
__device__ __forceinline__ unsigned short lvl_bf(float x) {
  unsigned short b1 = f2bf(x);
  if (L == 1) return b1;
  float r1 = x - bf2f(b1);
  unsigned short b2 = f2bf(r1);
  if (L == 2) return b2;
  return f2bf(r1 - bf2f(b2));
}

__device__ __forceinline__ void gll16(const unsigned short* g, unsigned short* l) {
  __builtin_amdgcn_global_load_lds(
      (const __attribute__((address_space(1))) unsigned int*)g,
      (__attribute__((address_space(3))) unsigned int*)l, 16, 0, 0);
}

// ---------------------------------------------------------------------------
// prep: W fragment stream, BK=64 tiles. Layout:
// [set][nb 0..7][tile j 0..35][fi 0..15][lane 0..63][8 shorts]
//   fi = kh*8 + wc*4 + g (kh 0..1); lane supplies row n = g*256+nb*32+wc*16+(l&15)
//   sk = jj*64 + kh*32 + (l>>4)*8 + e, jj = in-pass tile; lvl = sk/384; kk = sk%384.
// Blocks >= 576 zero-init h0 / c / tok (replaces host memsets).
// ---------------------------------------------------------------------------
__global__ void prep_weights(const float* __restrict__ eWih, const float* __restrict__ eWhh,
                             const float* __restrict__ dWih, const float* __restrict__ dWhh,
                             unsigned short* __restrict__ We, unsigned short* __restrict__ Wd,
                             float* __restrict__ h0, float* __restrict__ c,
                             int* __restrict__ tok)
{
  const int b = blockIdx.x;
  if (b >= 576) {                         // ---- init tail: 64 blocks
    const int pb = b - 576;
    const int gt = pb * 256 + threadIdx.x;     // 0..16383
    float4 z = make_float4(0.f, 0.f, 0.f, 0.f);
    float4* p0 = (float4*)h0;
    float4* pc = (float4*)c;
    for (int i = gt; i < 131072; i += 16384) { p0[i] = z; pc[i] = z; }
    if (gt < 2048) tok[gt] = 0;
    return;
  }
  const int j    = b % NTILE;
  const int rest = b / NTILE;
  const int nb   = rest & 7;
  const int set  = rest >> 3;
  const float* Wih = set ? dWih : eWih;
  const float* Whh = set ? dWhh : eWhh;
  unsigned short* dst = (set ? Wd : We) + ((size_t)nb * NTILE + j) * TILE_SHORTS;
  const int jj = (j < 18) ? j : (j < 30 ? j - 18 : j - 30);

  for (int cpos = threadIdx.x; cpos < 1024; cpos += 256) {
    int fi = cpos >> 6, l = cpos & 63;
    int kh = fi >> 3, wc = (fi >> 2) & 1, g = fi & 3;
    int n   = g * H_DIM + nb * 32 + wc * 16 + (l & 15);
    int sk0 = jj * 64 + kh * 32 + (l >> 4) * 8;
    int lvl = sk0 / 384;
    int kk  = sk0 - lvl * 384;
    unsigned short o8[8];
    #pragma unroll
    for (int e = 0; e < 8; ++e) {
      int k = kk + e;
      float v = (k < E_DIM) ? Wih[(size_t)n * E_DIM + k]
                            : Whh[(size_t)n * H_DIM + (k - E_DIM)];
      unsigned short b1 = f2bf(v);
      float r1 = v - bf2f(b1);
      unsigned short b2 = f2bf(r1);
      unsigned short b3 = f2bf(r1 - bf2f(b2));
      o8[e] = (lvl == 0) ? b1 : (lvl == 1) ? b2 : b3;
    }
    uint4 pk;
    pk.x = (unsigned)o8[0] | ((unsigned)o8[1] << 16);
    pk.y = (unsigned)o8[2] | ((unsigned)o8[3] << 16);
    pk.z = (unsigned)o8[4] | ((unsigned)o8[5] << 16);
    pk.w = (unsigned)o8[6] | ((unsigned)o8[7] << 16);
    *(uint4*)&dst[(size_t)cpos * 8] = pk;
  }
}

// stage level-L bf16 of A=[emb[idx]|h_in] into fragment layout:
// value (row, kA) -> Ax[((kA>>5)*4 + row>>4)*512 + ((row&15) + ((kA&31)>>3)*16)*8 + (kA&7)]
template<int L>
__device__ __forceinline__ void stage_A(unsigned short* Ax,
                                        const float* __restrict__ esrc,
                                        const float* __restrict__ hsrc,
                                        int arow, int q4) {
  const int rowblk = arow >> 4;
  const int rlo    = arow & 15;
  #pragma unroll
  for (int j = 0; j < 8; ++j) {
    int k0 = q4 * 4 + 16 * j;                 // 0..124, mult of 4
    float4 v = *(const float4*)(esrc + k0);
    unsigned short s0 = lvl_bf<L>(v.x), s1 = lvl_bf<L>(v.y),
                   s2 = lvl_bf<L>(v.z), s3 = lvl_bf<L>(v.w);
    uint2 p; p.x = (unsigned)s0 | ((unsigned)s1 << 16);
             p.y = (unsigned)s2 | ((unsigned)s3 << 16);
    int lane_w = rlo + ((k0 & 31) >> 3) * 16;
    *(uint2*)&Ax[(((k0 >> 5) * 4 + rowblk) * 64 + lane_w) * 8 + (k0 & 7)] = p;
  }
  #pragma unroll
  for (int j = 0; j < 16; ++j) {
    int k0 = q4 * 4 + 16 * j;                 // 0..252
    int kA = E_DIM + k0;
    float4 v = *(const float4*)(hsrc + k0);
    unsigned short s0 = lvl_bf<L>(v.x), s1 = lvl_bf<L>(v.y),
                   s2 = lvl_bf<L>(v.z), s3 = lvl_bf<L>(v.w);
    uint2 p; p.x = (unsigned)s0 | ((unsigned)s1 << 16);
             p.y = (unsigned)s2 | ((unsigned)s3 << 16);
    int lane_w = rlo + ((kA & 31) >> 3) * 16;
    *(uint2*)&Ax[(((kA >> 5) * 4 + rowblk) * 64 + lane_w) * 8 + (kA & 7)] = p;
  }
}

// ---------------------------------------------------------------------------
// LSTM step, bf16 triple-split 6-term MFMA (numerics identical to rounds 7/8).
// BK=64, 36 tiles, A+B both in pure fragment layout (all LDS reads lane-linear).
// LDS = 48 KB A + 32 KB B-dbuf = 80 KB exactly -> 2 blocks/CU.
// ---------------------------------------------------------------------------
__launch_bounds__(256, 2)
__global__ void lstm_mfma_kernel(const float* __restrict__ emb,
                                 const int* __restrict__ idx_src, int idx_stride, int idx_off,
                                 const unsigned short* __restrict__ Wf,
                                 const float* __restrict__ bih, const float* __restrict__ bhh,
                                 const float* __restrict__ h_in,
                                 float* __restrict__ h_out, float* __restrict__ c)
{
  __shared__ __align__(16) unsigned short smem[A_SHORTS + 2 * TILE_SHORTS]; // 81920 B
  unsigned short* Ax = smem;
  unsigned short* Bt0 = smem + A_SHORTS;
  unsigned short* Bt1 = smem + A_SHORTS + TILE_SHORTS;

  const int tid  = threadIdx.x;
  const int lane = tid & 63;
  const int w    = tid >> 6;
  const int m0 = blockIdx.x * 64;
  const int nb = blockIdx.y;

  const int arow = tid >> 2;
  const int q4   = tid & 3;
  const int token = idx_src[(size_t)(m0 + arow) * idx_stride + idx_off];
  const float* esrc = emb + (size_t)token * E_DIM;
  const float* hsrc = h_in + (size_t)(m0 + arow) * H_DIM;

  const unsigned short* wstream = Wf + (size_t)nb * (NTILE * TILE_SHORTS);

  // each wave stages its own 4 KB of the 16 KB tile (4 x gll16, linear dest)
  auto stage_B = [&](int j, unsigned short* dstb) {
    const unsigned short* src = wstream + (size_t)j * TILE_SHORTS + w * 2048 + lane * 8;
    unsigned short* dstp = dstb + w * 2048;
    #pragma unroll
    for (int i = 0; i < 4; ++i) gll16(src + i * 512, dstp + i * 512);
  };

  stage_A<1>(Ax, esrc, hsrc, arow, q4);
  stage_B(0, Bt0);
  __syncthreads();

  const int wm = (tid >> 6) & 1;
  const int wc = tid >> 7;

  f32x4v acc[2][4];
  #pragma unroll
  for (int mf = 0; mf < 2; ++mf)
    #pragma unroll
    for (int g = 0; g < 4; ++g)
      acc[mf][g] = (f32x4v){0.f, 0.f, 0.f, 0.f};

  #pragma unroll 1
  for (int j = 0; j < NTILE; ++j) {
    unsigned short* cur = (j & 1) ? Bt1 : Bt0;
    unsigned short* nxt = (j & 1) ? Bt0 : Bt1;
    if (j < NTILE - 1) stage_B(j + 1, nxt);
    const int jj  = (j < 18) ? j : (j < 30 ? j - 18 : j - 30);
    const int ks0 = (jj % 6) * 2;              // A ksub base for this tile
    #pragma unroll
    for (int kh = 0; kh < 2; ++kh) {
      bf16x8v af0 = *(const bf16x8v*)&Ax[((ks0 + kh) * 4 + wm * 2) * 512 + lane * 8];
      bf16x8v af1 = *(const bf16x8v*)&Ax[((ks0 + kh) * 4 + wm * 2 + 1) * 512 + lane * 8];
      #pragma unroll
      for (int g = 0; g < 4; ++g) {
        bf16x8v bfr = *(const bf16x8v*)&cur[(kh * 8 + wc * 4 + g) * 512 + lane * 8];
        acc[0][g] = __builtin_amdgcn_mfma_f32_16x16x32_bf16(af0, bfr, acc[0][g], 0, 0, 0);
        acc[1][g] = __builtin_amdgcn_mfma_f32_16x16x32_bf16(af1, bfr, acc[1][g], 0, 0, 0);
      }
    }
    __syncthreads();
    if (j == 17)      { stage_A<2>(Ax, esrc, hsrc, arow, q4); __syncthreads(); }
    else if (j == 29) { stage_A<3>(Ax, esrc, hsrc, arow, q4); __syncthreads(); }
  }

  // ---- epilogue: bias + cell update — exact round-7/8 version
  const int lr = tid & 15;
  const int l4 = lane >> 4;
  const int col = nb * 32 + wc * 16 + lr;
  float bs[4];
  #pragma unroll
  for (int g = 0; g < 4; ++g) bs[g] = bih[g * H_DIM + col] + bhh[g * H_DIM + col];

  #pragma unroll
  for (int mf = 0; mf < 2; ++mf) {
    #pragma unroll
    for (int r = 0; r < 4; ++r) {
      int row = m0 + wm * 32 + mf * 16 + l4 * 4 + r;
      float zi = acc[mf][0][r] + bs[0];
      float zf = acc[mf][1][r] + bs[1];
      float zg = acc[mf][2][r] + bs[2];
      float zo = acc[mf][3][r] + bs[3];
      float co = c[(size_t)row * H_DIM + col];
      float cn = sigf(zf) * co + sigf(zi) * tanhf(zg);
      c[(size_t)row * H_DIM + col] = cn;
      h_out[(size_t)row * H_DIM + col] = sigf(zo) * tanhf(cn);
    }
  }
}

// ---------------------------------------------------------------------------
// declog — round-2 math (bit-identical FMA order), staging double-buffered:
// 16 barriers instead of 32; LDS 72 KB -> 2 blocks/CU.
// ---------------------------------------------------------------------------
__launch_bounds__(256, 2)
__global__ void declog_kernel(const float* __restrict__ h,    // [B, H]
                              const float* __restrict__ fcW,  // [V, H]
                              const float* __restrict__ fcb,  // [V]
                              float* __restrict__ out,        // [B, T, V]
                              int* __restrict__ tok,          // [B]
                              int t, int T)
{
  __shared__ float As[8][264];
  __shared__ float Bs[2][16][V_DIM];

  const int tid  = threadIdx.x;
  const int lane = tid & 63;
  const int wv   = tid >> 6;
  const int r0   = blockIdx.x * 8;
  const int v0   = tid * 2;

  #pragma unroll
  for (int s = 0; s < 2; ++s) {
    int f4 = s * 256 + tid;
    int row = f4 >> 6, q = f4 & 63;
    float4 v = *(const float4*)(h + (size_t)(r0 + row) * H_DIM + q * 4);
    *(float4*)&As[row][q * 4] = v;
  }

  // stage tile 0 into Bs[0]
  {
    #pragma unroll
    for (int s = 0; s < 2; ++s) {
      const float* src = fcW + (size_t)(v0 + s) * H_DIM;
      float4 w0 = *(const float4*)(src + 0);
      float4 w1 = *(const float4*)(src + 4);
      float4 w2 = *(const float4*)(src + 8);
      float4 w3 = *(const float4*)(src + 12);
      float wr[16] = {w0.x, w0.y, w0.z, w0.w, w1.x, w1.y, w1.z, w1.w,
                      w2.x, w2.y, w2.z, w2.w, w3.x, w3.y, w3.z, w3.w};
      #pragma unroll
      for (int q = 0; q < 16; ++q) Bs[0][q][v0 + s] = wr[q];
    }
  }
  __syncthreads();

  float acc[2][8] = {};

  #pragma unroll 1
  for (int j = 0; j < 16; ++j) {
    const int buf = j & 1;
    float wr[2][16];
    if (j < 15) {
      #pragma unroll
      for (int s = 0; s < 2; ++s) {
        const float* src = fcW + (size_t)(v0 + s) * H_DIM + (j + 1) * 16;
        float4 w0 = *(const float4*)(src + 0);
        float4 w1 = *(const float4*)(src + 4);
        float4 w2 = *(const float4*)(src + 8);
        float4 w3 = *(const float4*)(src + 12);
        wr[s][0]=w0.x; wr[s][1]=w0.y; wr[s][2]=w0.z; wr[s][3]=w0.w;
        wr[s][4]=w1.x; wr[s][5]=w1.y; wr[s][6]=w1.z; wr[s][7]=w1.w;
        wr[s][8]=w2.x; wr[s][9]=w2.y; wr[s][10]=w2.z; wr[s][11]=w2.w;
        wr[s][12]=w3.x; wr[s][13]=w3.y; wr[s][14]=w3.z; wr[s][15]=w3.w;
      }
    }
    const int k0 = j * 16;
    #pragma unroll
    for (int kk = 0; kk < 16; ++kk) {
      float a0 = As[wv * 2 + 0][k0 + kk];
      float a1 = As[wv * 2 + 1][k0 + kk];
      #pragma unroll
      for (int i = 0; i < 8; ++i) {
        float b = Bs[buf][kk][lane + 64 * i];
        acc[0][i] = fmaf(a0, b, acc[0][i]);
        acc[1][i] = fmaf(a1, b, acc[1][i]);
      }
    }
    if (j < 15) {
      #pragma unroll
      for (int s = 0; s < 2; ++s)
        #pragma unroll
        for (int q = 0; q < 16; ++q) Bs[buf ^ 1][q][v0 + s] = wr[s][q];
    }
    __syncthreads();
  }

  float bias[8];
  #pragma unroll
  for (int i = 0; i < 8; ++i) bias[i] = fcb[lane + 64 * i];

  #pragma unroll
  for (int r = 0; r < 2; ++r) {
    int row = r0 + wv * 2 + r;
    float* op = out + (size_t)row * T * V_DIM + (size_t)t * V_DIM;
    float best = -INFINITY;
    int   bi   = 0x7fffffff;
    #pragma unroll
    for (int i = 0; i < 8; ++i) {
      float x = acc[r][i] + bias[i];
      op[lane + 64 * i] = x;
      if (x > best) { best = x; bi = lane + 64 * i; }
    }
    #pragma unroll
    for (int off = 32; off; off >>= 1) {
      float ov = __shfl_xor(best, off);
      int   oi = __shfl_xor(bi, off);
      if (ov > best || (ov == best && oi < bi)) { best = ov; bi = oi; }
    }
    if (lane == 0) tok[row] = bi;
  }
}

extern "C" void kernel_launch(void* const* d_in, const int* in_sizes, int n_in,
                              void* d_out, int out_size, void* d_ws, size_t ws_size,
                              hipStream_t stream) {
  const int*   source  = (const int*)d_in[0];
  const float* enc_emb = (const float*)d_in[2];
  const float* enc_Wih = (const float*)d_in[3];
  const float* enc_Whh = (const float*)d_in[4];
  const float* enc_bih = (const float*)d_in[5];
  const float* enc_bhh = (const float*)d_in[6];
  const float* dec_emb = (const float*)d_in[7];
  const float* dec_Wih = (const float*)d_in[8];
  const float* dec_Whh = (const float*)d_in[9];
  const float* dec_bih = (const float*)d_in[10];
  const float* dec_bhh = (const float*)d_in[11];
  const float* fc_W    = (const float*)d_in[12];
  const float* fc_b    = (const float*)d_in[13];
  float* out = (float*)d_out;

  const int B = in_sizes[0] / S_LEN;              // 2048
  const int T = out_size / (B * V_DIM);           // 48

  const size_t BH = (size_t)B * H_DIM;
  const size_t WFSZ = (size_t)8 * NTILE * TILE_SHORTS;   // shorts per set
  float* h0  = (float*)d_ws;
  float* h1  = h0 + BH;
  float* c   = h1 + BH;
  int*   tok = (int*)(c + BH);
  unsigned short* We = (unsigned short*)(tok + B);
  unsigned short* Wd = We + WFSZ;

  prep_weights<<<dim3(576 + 64), dim3(256), 0, stream>>>(
      enc_Wih, enc_Whh, dec_Wih, dec_Whh, We, Wd, h0, c, tok);

  dim3 blk(256);
  dim3 g_lstm(B / 64, H_DIM / 32);    // (32, 8) = 256 blocks
  dim3 g_declog(B / 8);               // 256 blocks

  const float* hin = h0;
  float* hout = h1;

  // ---- encoder ----
  for (int s = 0; s < S_LEN; ++s) {
    lstm_mfma_kernel<<<g_lstm, blk, 0, stream>>>(
        enc_emb, source, S_LEN, s, We, enc_bih, enc_bhh, hin, hout, c);
    const float* tmp = hout; hout = (float*)hin; hin = tmp;
  }

  // ---- decoder (greedy, autoregressive) ----
  for (int t = 0; t < T; ++t) {
    lstm_mfma_kernel<<<g_lstm, blk, 0, stream>>>(
        dec_emb, tok, 1, 0, Wd, dec_bih, dec_bhh, hin, hout, c);
    const float* tmp = hout; hout = (float*)hin; hin = tmp;
    declog_kernel<<<g_declog, blk, 0, stream>>>(hin, fc_W, fc_b, out, tok, t, T);
  }
}